// Round 1
// 220.370 us; speedup vs baseline: 1.0030x; 1.0030x over previous
//
#include <hip/hip_runtime.h>

#define B_    8
#define CIN   128
#define COUT  128
#define NX    8192
#define KMJ   32
#define MODES 256

typedef short bf16x8 __attribute__((ext_vector_type(8)));
typedef float f32x4  __attribute__((ext_vector_type(4)));

__device__ __forceinline__ float bf2f(unsigned short u) {
    union { unsigned int i; float f; } v; v.i = ((unsigned int)u) << 16; return v.f;
}
__device__ __forceinline__ unsigned short f2bf(float f) {
    union { float f; unsigned int i; } v; v.f = f;
    unsigned int x = v.i;
    return (unsigned short)((x + 0x7fffu + ((x >> 16) & 1u)) >> 16);
}
__device__ __forceinline__ bf16x8 cvt8(const float* __restrict__ p) {
    f32x4 a = *(const f32x4*)p;
    f32x4 b = *(const f32x4*)(p + 4);
    bf16x8 r;
    r[0] = (short)f2bf(a[0]); r[1] = (short)f2bf(a[1]);
    r[2] = (short)f2bf(a[2]); r[3] = (short)f2bf(a[3]);
    r[4] = (short)f2bf(b[0]); r[5] = (short)f2bf(b[1]);
    r[6] = (short)f2bf(b[2]); r[7] = (short)f2bf(b[3]);
    return r;
}
__device__ __forceinline__ ushort4 cvt4(f32x4 a) {
    ushort4 r;
    r.x = f2bf(a[0]); r.y = f2bf(a[1]); r.z = f2bf(a[2]); r.w = f2bf(a[3]);
    return r;
}

// ---------------------------------------------------------------------------
// K1 v2: Wk[k][o][i] = sum_j D[j][k] * weights[i][o][j]   (unchanged)
// ---------------------------------------------------------------------------
__global__ __launch_bounds__(256) void k1_wk(const float* __restrict__ W,
                                             const float* __restrict__ D,
                                             unsigned short* __restrict__ Wk) {
    int wave = threadIdx.x >> 6, lane = threadIdx.x & 63;
    int quad = lane >> 4, l16 = lane & 15;
    int gw  = blockIdx.x * 4 + wave;    // 0..1023 : n-tile of 16 over oi = o*128+i
    int oi0 = gw * 16;
    int i0  = oi0 & 127, o0 = oi0 >> 7; // oi0 16-aligned -> tile has fixed o
    bf16x8 bfrag = cvt8(W + ((size_t)(i0 + l16) * COUT + o0) * KMJ + quad * 8);
    for (int mt = 0; mt < 16; mt++) {
        int k0 = mt * 16;
        bf16x8 afrag;
#pragma unroll
        for (int jj = 0; jj < 8; jj++)
            afrag[jj] = (short)f2bf(D[(quad * 8 + jj) * MODES + k0 + l16]);
        f32x4 acc = {0.f, 0.f, 0.f, 0.f};
        acc = __builtin_amdgcn_mfma_f32_16x16x32_bf16(afrag, bfrag, acc, 0, 0, 0);
#pragma unroll
        for (int r = 0; r < 4; r++)
            Wk[(size_t)(k0 + quad * 4 + r) * (CIN * COUT) + oi0 + l16] = f2bf(acc[r]);
    }
}

// ---------------------------------------------------------------------------
// K2 v4: PART[b][nt][c][k] = sum_{n in nt-chunk} x[b][c][n]*wb[b][n][k]  (bf16)
//
// Round-0 counters: MfmaUtil 3.3%, VALUBusy 8.5%, HBM 18%, Occ 16.6% ->
// latency-bound, not BW-bound. Changes vs v3:
//   1. blockIdx.z splits MODES in 2 halves -> 512 blocks = 2 blocks/CU,
//      4 waves/SIMD (was 1 block/CU, 2 waves/SIMD). Cross-block overlap.
//   2. Register prefetch of step s+1 issued before MFMA(s) (k4 pattern) --
//      kills the serialized load->barrier->compute per-step bursts.
//   3. WB staged TRANSPOSED [k][n] (staircase layout, 16B-aligned rows,
//      bank-uniform) -> B-frags are ds_read_b128 instead of 32x ds_read_u16.
// PART layout and n-accumulation order unchanged -> bitwise-same output.
// ---------------------------------------------------------------------------
__global__ __launch_bounds__(512, 4) void k2_xhat(const float* __restrict__ X,
                                                  const float* __restrict__ WB,
                                                  unsigned short* __restrict__ PART) {
    __shared__ __align__(16) unsigned short Xs[128 * 40];   // [c][40], cols 0..31
    __shared__ __align__(16) unsigned short WBT[8 * 552];   // staircase [k][n], k 0..127
    int nt = blockIdx.x, b = blockIdx.y, kh = blockIdx.z;
    int r0 = nt * 256;
    int t  = threadIdx.x;
    int wave = t >> 6, lane = t & 63;
    int wm = wave >> 1, wn = wave & 1;          // wave tile: 32c x 64k of 128x128
    int quad = lane >> 4, l16 = lane & 15;

    const float* xb  = X  + (size_t)b * CIN * NX;
    const float* wbb = WB + (size_t)b * NX * MODES + kh * 128;

    // staging roles: waves 4..7 stage X (4 f32x4), waves 0..3 stage WB (4 f32x4)
    bool isX = (t >= 256);
    int t2 = t & 255;
    int xn4 = t2 & 7,  xc = t2 >> 3;   // X:  c = xc + 32r, n = 4*xn4..+3
    int kq  = t2 & 31, nq = t2 >> 5;   // WB: k = 4*kq + j, n = 4*nq + r

    f32x4 acc[2][4];
#pragma unroll
    for (int i = 0; i < 2; i++)
#pragma unroll
        for (int j = 0; j < 4; j++) acc[i][j] = (f32x4){0.f, 0.f, 0.f, 0.f};

    // preload step 0 into registers
    f32x4 st[4];
    if (isX) {
#pragma unroll
        for (int r = 0; r < 4; r++)
            st[r] = *(const f32x4*)(xb + (size_t)(xc + 32 * r) * NX + r0 + 4 * xn4);
    } else {
#pragma unroll
        for (int r = 0; r < 4; r++)
            st[r] = *(const f32x4*)(wbb + (size_t)(r0 + 4 * nq + r) * MODES + 4 * kq);
    }

    for (int s = 0; s < 8; s++) {
        __syncthreads();   // previous step's frag reads complete
        if (isX) {
#pragma unroll
            for (int r = 0; r < 4; r++)
                *(ushort4*)(Xs + (xc + 32 * r) * 40 + 4 * xn4) = cvt4(st[r]);
        } else {
            // register 4x4 transpose: write 4 consecutive n at fixed k
#pragma unroll
            for (int j = 0; j < 4; j++) {
                int k = 4 * kq + j;
                ushort4 w;
                w.x = f2bf(st[0][j]); w.y = f2bf(st[1][j]);
                w.z = f2bf(st[2][j]); w.w = f2bf(st[3][j]);
                *(ushort4*)(WBT + (k >> 4) * 552 + (k & 15) * 32 + ((k >> 2) & 3) * 8 + 4 * nq) = w;
            }
        }
        __syncthreads();   // staging visible

        if (s < 7) {       // prefetch s+1; drains during frag reads + MFMA below
            int rs = r0 + (s + 1) * 32;
            if (isX) {
#pragma unroll
                for (int r = 0; r < 4; r++)
                    st[r] = *(const f32x4*)(xb + (size_t)(xc + 32 * r) * NX + rs + 4 * xn4);
            } else {
#pragma unroll
                for (int r = 0; r < 4; r++)
                    st[r] = *(const f32x4*)(wbb + (size_t)(rs + 4 * nq + r) * MODES + 4 * kq);
            }
        }

        bf16x8 af[2], bfv[4];
#pragma unroll
        for (int tm = 0; tm < 2; tm++)
            af[tm] = *(const bf16x8*)(Xs + (wm * 32 + tm * 16 + l16) * 40 + quad * 8);
#pragma unroll
        for (int tn = 0; tn < 4; tn++) {
            int km = wn * 64 + tn * 16 + l16;
            bfv[tn] = *(const bf16x8*)(WBT + (km >> 4) * 552 + (km & 15) * 32 + ((km >> 2) & 3) * 8 + quad * 8);
        }
#pragma unroll
        for (int tm = 0; tm < 2; tm++)
#pragma unroll
            for (int tn = 0; tn < 4; tn++)
                acc[tm][tn] = __builtin_amdgcn_mfma_f32_16x16x32_bf16(af[tm], bfv[tn], acc[tm][tn], 0, 0, 0);
    }

    unsigned short* pb = PART + ((size_t)b * 32 + nt) * (CIN * MODES) + kh * 128;
#pragma unroll
    for (int tm = 0; tm < 2; tm++) {
        int c = wm * 32 + tm * 16 + quad * 4;
#pragma unroll
        for (int tn = 0; tn < 4; tn++) {
            int km = wn * 64 + tn * 16 + l16;
#pragma unroll
            for (int r = 0; r < 4; r++)
                pb[(size_t)(c + r) * MODES + km] = f2bf(acc[tm][tn][r]);
        }
    }
}

// ---------------------------------------------------------------------------
// K2b: XH[b][c][k] = sum_nt PART[b][nt][c][k]   (unchanged)
// ---------------------------------------------------------------------------
__global__ __launch_bounds__(256) void k2b_red(const unsigned short* __restrict__ PART,
                                               float* __restrict__ XH) {
    int e0 = blockIdx.x * 1024 + threadIdx.x;
#pragma unroll
    for (int r = 0; r < 4; r++) {
        int e = e0 + r * 256;                  // 0..262143
        int b = e >> 15, rem = e & 32767;
        const unsigned short* p = PART + (size_t)b * 32 * (CIN * MODES) + rem;
        float acc = 0.f;
#pragma unroll
        for (int nt = 0; nt < 32; nt++) acc += bf2f(p[nt * (CIN * MODES)]);
        XH[e] = acc;
    }
}

// ---------------------------------------------------------------------------
// K3 v2: y_hat[b][o][k] = sum_i x_hat[b][i][k] * Wk[k][o][i]   (unchanged)
// ---------------------------------------------------------------------------
__global__ __launch_bounds__(256) void k3_yhat(const float* __restrict__ XH,
                                               const unsigned short* __restrict__ Wk,
                                               unsigned short* __restrict__ YH) {
    __shared__ float xs[128][8];
    int k = blockIdx.x;
    int t = threadIdx.x;
#pragma unroll
    for (int l = 0; l < 4; l++) {
        int e = l * 256 + t;                   // 0..1023
        int i = e >> 3, b = e & 7;
        xs[i][b] = XH[(size_t)b * (CIN * MODES) + (size_t)i * MODES + k];
    }
    __syncthreads();
    int o = t & 127, bh = t >> 7;              // bh: b-half (4 b's each)
    const unsigned short* wp = Wk + (size_t)k * (CIN * COUT) + (size_t)o * CIN;
    f32x4 acc = {0.f, 0.f, 0.f, 0.f};
    for (int ii = 0; ii < 16; ii++) {
        bf16x8 wc = *(const bf16x8*)(wp + ii * 8);
#pragma unroll
        for (int jj = 0; jj < 8; jj++) {
            float w = bf2f((unsigned short)wc[jj]);
            f32x4 xv = *(const f32x4*)&xs[ii * 8 + jj][bh * 4];
            acc += w * xv;
        }
    }
#pragma unroll
    for (int r = 0; r < 4; r++)
        YH[((size_t)(bh * 4 + r) * COUT + o) * MODES + k] = f2bf(acc[r]);
}

// ---------------------------------------------------------------------------
// K4 v2: y[b][c][n] = sum_k y_hat[b][c][k] * bases[b][n][k]   (unchanged)
// ---------------------------------------------------------------------------
__global__ __launch_bounds__(256) void k4_y(const unsigned short* __restrict__ YH,
                                            const float* __restrict__ BA,
                                            float* __restrict__ Y) {
    __shared__ __align__(16) unsigned short As[128 * 32];
    __shared__ __align__(16) unsigned short Bs[128 * 32];
    int b  = blockIdx.y;
    int n0 = blockIdx.x * 128;
    int t  = threadIdx.x;
    int wave = t >> 6, lane = t & 63;
    int wm = wave >> 1, wn = wave & 1;
    int quad = lane >> 4, l16 = lane & 15;

    const unsigned short* yhb = YH + (size_t)b * COUT * MODES;
    const float* bab = BA + (size_t)b * NX * MODES + (size_t)n0 * MODES;

    int E0 = t * 8;              // chunk p: element E = p*2048 + E0
    int row0 = E0 >> 5, kk0 = E0 & 31;
    int row1 = (2048 + E0) >> 5, kk1 = (2048 + E0) & 31;

    f32x4 acc[4][4];
#pragma unroll
    for (int i = 0; i < 4; i++)
#pragma unroll
        for (int j = 0; j < 4; j++) acc[i][j] = (f32x4){0.f, 0.f, 0.f, 0.f};

    // preload step 0
    bf16x8 av0 = *(const bf16x8*)(yhb + (size_t)row0 * MODES + kk0);
    bf16x8 av1 = *(const bf16x8*)(yhb + (size_t)row1 * MODES + kk1);
    f32x4 bv0a = *(const f32x4*)(bab + (size_t)row0 * MODES + kk0);
    f32x4 bv0b = *(const f32x4*)(bab + (size_t)row0 * MODES + kk0 + 4);
    f32x4 bv1a = *(const f32x4*)(bab + (size_t)row1 * MODES + kk1);
    f32x4 bv1b = *(const f32x4*)(bab + (size_t)row1 * MODES + kk1 + 4);

    for (int step = 0; step < 8; step++) {
        __syncthreads();   // previous step's frag reads complete (no-op at s=0)
        *(bf16x8*)(As + E0)        = av0;
        *(bf16x8*)(As + 2048 + E0) = av1;
        bf16x8 bs0, bs1;
        bs0[0]=(short)f2bf(bv0a[0]); bs0[1]=(short)f2bf(bv0a[1]);
        bs0[2]=(short)f2bf(bv0a[2]); bs0[3]=(short)f2bf(bv0a[3]);
        bs0[4]=(short)f2bf(bv0b[0]); bs0[5]=(short)f2bf(bv0b[1]);
        bs0[6]=(short)f2bf(bv0b[2]); bs0[7]=(short)f2bf(bv0b[3]);
        bs1[0]=(short)f2bf(bv1a[0]); bs1[1]=(short)f2bf(bv1a[1]);
        bs1[2]=(short)f2bf(bv1a[2]); bs1[3]=(short)f2bf(bv1a[3]);
        bs1[4]=(short)f2bf(bv1b[0]); bs1[5]=(short)f2bf(bv1b[1]);
        bs1[6]=(short)f2bf(bv1b[2]); bs1[7]=(short)f2bf(bv1b[3]);
        *(bf16x8*)(Bs + E0)        = bs0;
        *(bf16x8*)(Bs + 2048 + E0) = bs1;
        __syncthreads();   // staging visible

        if (step < 7) {    // prefetch s+1 into regs; drains during MFMA below
            int ks = (step + 1) * 32;
            av0  = *(const bf16x8*)(yhb + (size_t)row0 * MODES + ks + kk0);
            av1  = *(const bf16x8*)(yhb + (size_t)row1 * MODES + ks + kk1);
            bv0a = *(const f32x4*)(bab + (size_t)row0 * MODES + ks + kk0);
            bv0b = *(const f32x4*)(bab + (size_t)row0 * MODES + ks + kk0 + 4);
            bv1a = *(const f32x4*)(bab + (size_t)row1 * MODES + ks + kk1);
            bv1b = *(const f32x4*)(bab + (size_t)row1 * MODES + ks + kk1 + 4);
        }

        bf16x8 af[4], bfv[4];
#pragma unroll
        for (int tm = 0; tm < 4; tm++) {
            int c = wm * 64 + tm * 16 + l16;
            af[tm] = *(const bf16x8*)(As + c * 32 + quad * 8);
        }
#pragma unroll
        for (int tn = 0; tn < 4; tn++) {
            int n = wn * 64 + tn * 16 + l16;
            bfv[tn] = *(const bf16x8*)(Bs + n * 32 + quad * 8);
        }
#pragma unroll
        for (int tm = 0; tm < 4; tm++)
#pragma unroll
            for (int tn = 0; tn < 4; tn++)
                acc[tm][tn] = __builtin_amdgcn_mfma_f32_16x16x32_bf16(af[tm], bfv[tn], acc[tm][tn], 0, 0, 0);
    }

    float* yb = Y + (size_t)b * COUT * NX;
#pragma unroll
    for (int tm = 0; tm < 4; tm++) {
        int o = wm * 64 + tm * 16 + quad * 4;
#pragma unroll
        for (int tn = 0; tn < 4; tn++) {
            int n = n0 + wn * 64 + tn * 16 + l16;
#pragma unroll
            for (int r = 0; r < 4; r++)
                yb[(size_t)(o + r) * NX + n] = acc[tm][tn][r];
        }
    }
}

extern "C" void kernel_launch(void* const* d_in, const int* in_sizes, int n_in,
                              void* d_out, int out_size, void* d_ws, size_t ws_size,
                              hipStream_t stream) {
    const float* X  = (const float*)d_in[0];  // [8][128][8192]
    const float* WB = (const float*)d_in[1];  // [8][8192][256]
    const float* BA = (const float*)d_in[2];  // [8][8192][256]
    const float* W  = (const float*)d_in[3];  // [128][128][32]
    const float* D  = (const float*)d_in[4];  // [32][256]
    float* Y = (float*)d_out;                 // [8][128][8192]

    char* ws = (char*)d_ws;
    unsigned short* Wk   = (unsigned short*)ws;                  // 8 MB bf16 [k][o][i]
    float*          XH   = (float*)(ws + (8u << 20));            // 1 MB fp32 [b][c][k]
    unsigned short* YH   = (unsigned short*)(ws + (9u << 20));   // 0.5 MB bf16 [b][o][k]
    unsigned short* PART = (unsigned short*)(ws + (10u << 20));  // 16.75 MB bf16 [b][nt][c][k]

    k1_wk  <<<256,            256, 0, stream>>>(W, D, Wk);
    k2_xhat<<<dim3(32, 8, 2), 512, 0, stream>>>(X, WB, PART);
    k2b_red<<<256,            256, 0, stream>>>(PART, XH);
    k3_yhat<<<MODES,          256, 0, stream>>>(XH, Wk, YH);
    k4_y   <<<dim3(64, 8),    256, 0, stream>>>(YH, BA, Y);
}